// Round 9
// baseline (571.007 us; speedup 1.0000x reference)
//
#include <hip/hip_runtime.h>
#include <hip/hip_bf16.h>

#define NSEG 512
#define HID 768

typedef __attribute__((ext_vector_type(8))) short s16x8;
typedef __attribute__((ext_vector_type(8))) unsigned short u16x8;
typedef __attribute__((ext_vector_type(4))) unsigned short u16x4;
typedef __attribute__((ext_vector_type(4))) float f32x4;

__device__ __forceinline__ unsigned short f2bf(float x) {
  unsigned u = __builtin_bit_cast(unsigned, x);
  unsigned r = (u + 0x7fff + ((u >> 16) & 1)) >> 16;   // RNE
  return (unsigned short)r;
}

__device__ __forceinline__ float bf2f(unsigned short h) {
  unsigned u = ((unsigned)h) << 16;
  return __builtin_bit_cast(float, u);
}

__device__ __forceinline__ void gl_lds16(const void* g, void* l) {
  __builtin_amdgcn_global_load_lds(
      (const __attribute__((address_space(1))) unsigned*)g,
      (__attribute__((address_space(3))) unsigned*)l, 16, 0, 0);
}

// ---------------- fused index-compose chains ----------------
__global__ __launch_bounds__(256)
void compose4_k(int* __restrict__ c42, int* __restrict__ c41, int* __restrict__ c40,
                const int* __restrict__ inv4, const int* __restrict__ inv3,
                const int* __restrict__ inv2, const int* __restrict__ inv1, int total) {
  int t = blockIdx.x * 256 + threadIdx.x;
  if (t >= total) return;
  int b = (t >= 65536) ? 1 : 0;
  int n3 = inv4[t];
  int n2 = inv3[b * 16384 + n3]; c42[t] = n2;
  int n1 = inv2[b * 4096  + n2]; c41[t] = n1;
  int n0 = inv1[b * 1024  + n1]; c40[t] = n0;
}

__global__ __launch_bounds__(256)
void compose3_k(int* __restrict__ c31, int* __restrict__ c30,
                const int* __restrict__ inv3, const int* __restrict__ inv2,
                const int* __restrict__ inv1, int total) {
  int t = blockIdx.x * 256 + threadIdx.x;
  if (t >= total) return;
  int b = (t >= 16384) ? 1 : 0;
  int n2 = inv3[t];
  int n1 = inv2[b * 4096 + n2]; c31[t] = n1;
  int n0 = inv1[b * 1024 + n1]; c30[t] = n0;
}

__global__ __launch_bounds__(256)
void compose2_k(int* __restrict__ c20, const int* __restrict__ inv2,
                const int* __restrict__ inv1, int total) {
  int t = blockIdx.x * 256 + threadIdx.x;
  if (t >= total) return;
  int b = (t >= 4096) ? 1 : 0;
  c20[t] = inv1[b * 1024 + inv2[t]];
}

// ---------------- histogram ----------------
__global__ __launch_bounds__(256)
void hist_k(int* __restrict__ cnt, const int* __restrict__ p2s, int N, int total) {
  int t = blockIdx.x * 256 + threadIdx.x;
  if (t >= total) return;
  int b = (t >= N) ? 1 : 0;
  atomicAdd(&cnt[b * NSEG + p2s[t]], 1);
}

// ---------------- scan + 1/m ----------------
__global__ __launch_bounds__(512)
void scan_k(const int* __restrict__ cnt, int* __restrict__ off, float* __restrict__ scl) {
  __shared__ int sm[NSEG];
  int base = blockIdx.x * NSEG;
  int t = threadIdx.x;
  int v = cnt[base + t];
  sm[t] = v;
  __syncthreads();
  for (int d = 1; d < NSEG; d <<= 1) {
    int u = (t >= d) ? sm[t - d] : 0;
    __syncthreads();
    sm[t] += u;
    __syncthreads();
  }
  off[base + t] = sm[t] - v;
  scl[base + t] = 1.0f / (float)(v > 0 ? v : 1);
}

// ---------------- scatter point ids ----------------
__global__ __launch_bounds__(256)
void scat_k(int* __restrict__ pt, int* __restrict__ cur, const int* __restrict__ off,
            const int* __restrict__ p2s, int N, int total) {
  int t = blockIdx.x * 256 + threadIdx.x;
  if (t >= total) return;
  int b = (t >= N) ? 1 : 0;
  int n = t - b * N;
  int idx = b * NSEG + p2s[t];
  int pos = off[idx] + atomicAdd(&cur[idx], 1);
  pt[b * N + pos] = n;
}

// ---------------- reduce args (fp32 gathers) ----------------
struct RedArgs {
  const float* x[5];
  const int*  ci[5];
  int Nj[5];
  int CN[5];
  int OFF[5];
  int nb;
  int N;
  int CF;
};

// ---------------- levels 0/1: full-channel, 256-thr, direct fp32 seg write ----------------
__global__ __launch_bounds__(256)
void reduce2_k(RedArgs a, const int* __restrict__ pt, const int* __restrict__ cnt,
               const int* __restrict__ off, float* __restrict__ seg) {
  int bs = blockIdx.x;
  int b  = bs >> 9;
  int t  = threadIdx.x;
  int m  = cnt[bs];

  int c4 = t * 4;
  bool val = c4 < a.CF;
  const float* xs = nullptr; const int* cim = nullptr; int str = 1;
  if (val) {
    int j = 0;
    while (j < a.nb - 1 && !(c4 >= a.OFF[j] && c4 < a.OFF[j] + a.CN[j])) j++;
    xs  = a.x[j] + (size_t)b * a.Nj[j] * a.CN[j] + (c4 - a.OFF[j]);
    cim = a.ci[j] ? (a.ci[j] + (size_t)b * a.N) : nullptr;
    str = a.CN[j];
  }

  float a0 = 0.f, a1 = 0.f, a2 = 0.f, a3 = 0.f;
  if (val && m > 0) {
    const int* pl = pt + (size_t)b * a.N + off[bs];
    int p = 0;
    for (; p + 4 <= m; p += 4) {
      int n0 = pl[p], n1 = pl[p + 1], n2 = pl[p + 2], n3 = pl[p + 3];
      int r0 = cim ? cim[n0] : n0;
      int r1 = cim ? cim[n1] : n1;
      int r2 = cim ? cim[n2] : n2;
      int r3 = cim ? cim[n3] : n3;
      float4 v0 = *(const float4*)(xs + (size_t)r0 * str);
      float4 v1 = *(const float4*)(xs + (size_t)r1 * str);
      float4 v2 = *(const float4*)(xs + (size_t)r2 * str);
      float4 v3 = *(const float4*)(xs + (size_t)r3 * str);
      a0 += (v0.x + v1.x) + (v2.x + v3.x);
      a1 += (v0.y + v1.y) + (v2.y + v3.y);
      a2 += (v0.z + v1.z) + (v2.z + v3.z);
      a3 += (v0.w + v1.w) + (v2.w + v3.w);
    }
    for (; p < m; p++) {
      int n0 = pl[p];
      int r0 = cim ? cim[n0] : n0;
      float4 v0 = *(const float4*)(xs + (size_t)r0 * str);
      a0 += v0.x; a1 += v0.y; a2 += v0.z; a3 += v0.w;
    }
  }
  if (val)
    *(float4*)(seg + (size_t)bs * a.CF + c4) = make_float4(a0, a1, a2, a3);
}

// ---------------- levels 2-4: XCD-pinned channel-sliced chunked reduce ----------------
// grid (8, 1024, NC), block 64. slice = blockIdx.x = linear_wid % 8 -> one XCD.
// lane t owns interleaved channel-group g = t*8 + slice  (each table sliced
// 8-way evenly -> per-XCD reused working set ~tables/8, L2-resident).
// Writes bf16 partials part[chunk][row][CF] — no atomics, no pre-zeroing.
__global__ __launch_bounds__(64)
void reduce_sl_k(RedArgs a, const int* __restrict__ pt, const int* __restrict__ cnt,
                 const int* __restrict__ off, unsigned short* __restrict__ part, int nchunk) {
  int slice = blockIdx.x;            // 0..7
  int bs    = blockIdx.y;            // b*512 + s
  int chunk = blockIdx.z;
  int b  = bs >> 9;
  int t  = threadIdx.x;
  int g  = t * 8 + slice;            // interleaved group id
  int groups = a.CF >> 2;
  bool val = g < groups;
  int c4 = g * 4;

  const float* xs = nullptr; const int* cim = nullptr; int str = 1;
  if (val) {
    int j = 0;
    while (j < a.nb - 1 && !(c4 >= a.OFF[j] && c4 < a.OFF[j] + a.CN[j])) j++;
    xs  = a.x[j] + (size_t)b * a.Nj[j] * a.CN[j] + (c4 - a.OFF[j]);
    cim = a.ci[j] ? (a.ci[j] + (size_t)b * a.N) : nullptr;
    str = a.CN[j];
  }

  int m = cnt[bs];
  int cs = (m + nchunk - 1) / nchunk;
  int start = chunk * cs;
  int end = min(m, start + cs);

  float a0 = 0.f, a1 = 0.f, a2 = 0.f, a3 = 0.f;
  if (val && start < end) {
    const int* pl = pt + (size_t)b * a.N + off[bs];
    int p = start;
    for (; p + 4 <= end; p += 4) {
      int n0 = pl[p], n1 = pl[p + 1], n2 = pl[p + 2], n3 = pl[p + 3];
      int r0 = cim ? cim[n0] : n0;
      int r1 = cim ? cim[n1] : n1;
      int r2 = cim ? cim[n2] : n2;
      int r3 = cim ? cim[n3] : n3;
      float4 v0 = *(const float4*)(xs + (size_t)r0 * str);
      float4 v1 = *(const float4*)(xs + (size_t)r1 * str);
      float4 v2 = *(const float4*)(xs + (size_t)r2 * str);
      float4 v3 = *(const float4*)(xs + (size_t)r3 * str);
      a0 += (v0.x + v1.x) + (v2.x + v3.x);
      a1 += (v0.y + v1.y) + (v2.y + v3.y);
      a2 += (v0.z + v1.z) + (v2.z + v3.z);
      a3 += (v0.w + v1.w) + (v2.w + v3.w);
    }
    for (; p < end; p++) {
      int n0 = pl[p];
      int r0 = cim ? cim[n0] : n0;
      float4 v0 = *(const float4*)(xs + (size_t)r0 * str);
      a0 += v0.x; a1 += v0.y; a2 += v0.z; a3 += v0.w;
    }
  }

  if (val) {
    unsigned short* po = part + ((size_t)chunk * 1024 + bs) * a.CF + c4;
    u16x4 o = {f2bf(a0), f2bf(a1), f2bf(a2), f2bf(a3)};
    *(u16x4*)po = o;
  }
}

// ---------------- combine partials + scale + bf16 + chunk-swizzle + K-pad ----------------
struct CsArgs {
  const float* sg[2];              // levels 0,1: fp32 seg sums
  const unsigned short* pp[5];     // levels 2..4: bf16 partials [NC][1024][CF]
  unsigned short* sb[5];
  const float* scl;
  int CF[5]; int KP[5]; int NC[5];
};

__global__ __launch_bounds__(256)
void conv_seg_k(CsArgs a) {
  int row = blockIdx.x;            // 0..5119
  int lvl = row >> 10;
  int rl  = row & 1023;
  int CF = a.CF[lvl], KP = a.KP[lvl];
  int c = threadIdx.x;
  if (c >= (KP >> 3)) return;
  float s = a.scl[row];
  int w = c & 7, blk = c >> 3;
  int k0 = blk * 64 + ((w ^ (rl & 7)) << 3);
  u16x8 o = {0, 0, 0, 0, 0, 0, 0, 0};
  if (k0 < CF) {
    float acc[8] = {};
    if (lvl <= 1) {
      const float* src = a.sg[lvl] + (size_t)rl * CF + k0;
      float4 v0 = *(const float4*)src;
      float4 v1 = *(const float4*)(src + 4);
      acc[0] = v0.x; acc[1] = v0.y; acc[2] = v0.z; acc[3] = v0.w;
      acc[4] = v1.x; acc[5] = v1.y; acc[6] = v1.z; acc[7] = v1.w;
    } else {
      int nc = a.NC[lvl];
      const unsigned short* base = a.pp[lvl] + (size_t)rl * CF + k0;
      for (int n = 0; n < nc; n++) {
        u16x8 v = *(const u16x8*)(base + (size_t)n * 1024 * CF);
#pragma unroll
        for (int e = 0; e < 8; e++) acc[e] += bf2f(v[e]);
      }
    }
#pragma unroll
    for (int e = 0; e < 8; e++) o[e] = f2bf(acc[e] * s);
  }
  *(u16x8*)(a.sb[lvl] + (size_t)rl * KP + c * 8) = o;
}

// ---------------- W [CF][768] fp32 -> Wt [768][KP] bf16 transposed+swizzled ----------------
struct CwArgs { const float* w[5]; unsigned short* wt[5]; int CF[5]; int KP[5]; };

__global__ __launch_bounds__(256)
void conv_wt_k(CwArgs a) {
  int lvl = blockIdx.y;
  int KP = a.KP[lvl], CF = a.CF[lvl];
  int idx = blockIdx.x * 256 + threadIdx.x;
  if (idx >= 768 * (KP >> 3)) return;
  int c = idx / 768;
  int n = idx - c * 768;
  int w = c & 7, blk = c >> 3;
  int k0 = blk * 64 + ((w ^ (n & 7)) << 3);
  u16x8 o = {0, 0, 0, 0, 0, 0, 0, 0};
  if (k0 < CF) {
    const float* src = a.w[lvl] + (size_t)k0 * HID + n;
#pragma unroll
    for (int e = 0; e < 8; e++) o[e] = f2bf(src[(size_t)e * HID]);
  }
  *(u16x8*)(a.wt[lvl] + (size_t)n * KP + c * 8) = o;
}

// ---------------- bf16 MFMA GEMM: proj = segbf @ Wt^T + bias ----------------
struct G2Args {
  const unsigned short* sb[5];
  const unsigned short* wt[5];
  const float* bias[5];
  float* proj;
  int KP[5];
  int KIT[5];
};

__global__ __launch_bounds__(256)
void gemm2_k(G2Args g) {
  int lvl = blockIdx.z;
  int n0 = blockIdx.x * 64;
  int m0 = blockIdx.y * 128;
  const char* A = (const char*)g.sb[lvl];
  const char* Bw = (const char*)g.wt[lvl];
  int KP = g.KP[lvl];
  int KIT = g.KIT[lvl];

  __shared__ char smem[49152];     // 2 x (16KB A + 8KB B)

  int t = threadIdx.x;
  int lane = t & 63;
  int w = t >> 6;
  int wm = w >> 1, wn = w & 1;

  f32x4 acc[4][2] = {};

  int rowb = t >> 3;
  int colb = (t & 7) * 16;

  auto stg = [&](int buf, int it) {
    char* base = smem + buf * 24576;
#pragma unroll
    for (int j = 0; j < 4; j++) {
      int row = j * 32 + rowb;
      gl_lds16(A + (size_t)(m0 + row) * (KP * 2) + it * 128 + colb,
               base + j * 4096 + t * 16);
    }
#pragma unroll
    for (int j = 0; j < 2; j++) {
      int row = j * 32 + rowb;
      gl_lds16(Bw + (size_t)(n0 + row) * (KP * 2) + it * 128 + colb,
               base + 16384 + j * 4096 + t * 16);
    }
  };

  int r15 = lane & 15, hi = lane >> 4, sx = (lane & 7) << 4;

  stg(0, 0);
  int cur = 0;
  for (int it = 0; it < KIT; ++it) {
    __syncthreads();
    if (it + 1 < KIT) stg(cur ^ 1, it + 1);
    const char* base = smem + cur * 24576;
    s16x8 af[2][4]; s16x8 bf2v[2][2];
#pragma unroll
    for (int s = 0; s < 2; s++) {
      int cb = (s * 64 + hi * 16) ^ sx;
#pragma unroll
      for (int fm = 0; fm < 4; fm++) {
        int row = wm * 64 + fm * 16 + r15;
        af[s][fm] = *(const s16x8*)(base + row * 128 + cb);
      }
#pragma unroll
      for (int fn = 0; fn < 2; fn++) {
        int row = wn * 32 + fn * 16 + r15;
        bf2v[s][fn] = *(const s16x8*)(base + 16384 + row * 128 + cb);
      }
    }
#pragma unroll
    for (int s = 0; s < 2; s++)
#pragma unroll
      for (int fm = 0; fm < 4; fm++)
#pragma unroll
        for (int fn = 0; fn < 2; fn++)
          acc[fm][fn] = __builtin_amdgcn_mfma_f32_16x16x32_bf16(af[s][fm], bf2v[s][fn], acc[fm][fn], 0, 0, 0);
    cur ^= 1;
  }

  const float* bias = g.bias[lvl];
  float* proj = g.proj + ((size_t)lvl * 1024 + m0) * HID;
#pragma unroll
  for (int fm = 0; fm < 4; fm++)
#pragma unroll
    for (int fn = 0; fn < 2; fn++) {
      int col = n0 + wn * 32 + fn * 16 + r15;
      int rb = wm * 64 + fm * 16 + hi * 4;
      float bi = bias[col];
      f32x4 v = acc[fm][fn];
#pragma unroll
      for (int r = 0; r < 4; r++)
        proj[(size_t)(rb + r) * HID + col] = v[r] + bi;
    }
}

// ---------------- LayerNorm over HID=768 (fp32 in/out) ----------------
struct LnArgs { const float* g[5]; const float* be[5]; };

__global__ __launch_bounds__(256)
void ln_k(LnArgs la, const float* __restrict__ proj, float* __restrict__ out) {
  int row = blockIdx.x;
  int lvl = row >> 10;
  const float* x = proj + (size_t)row * HID;
  int t = threadIdx.x;
  float v0 = x[t], v1 = x[t + 256], v2 = x[t + 512];
  float s = v0 + v1 + v2;
  float q = v0 * v0 + v1 * v1 + v2 * v2;
#pragma unroll
  for (int d = 32; d >= 1; d >>= 1) { s += __shfl_down(s, d); q += __shfl_down(q, d); }
  __shared__ float ps[4], pq[4];
  int w = t >> 6;
  if ((t & 63) == 0) { ps[w] = s; pq[w] = q; }
  __syncthreads();
  float S = ps[0] + ps[1] + ps[2] + ps[3];
  float Q = pq[0] + pq[1] + pq[2] + pq[3];
  float mean = S * (1.0f / HID);
  float var  = Q * (1.0f / HID) - mean * mean;
  float rs   = rsqrtf(var + 1e-5f);
  const float* g  = la.g[lvl];
  const float* be = la.be[lvl];
  float* o = out + (size_t)row * HID;
  o[t]       = (v0 - mean) * rs * g[t]       + be[t];
  o[t + 256] = (v1 - mean) * rs * g[t + 256] + be[t + 256];
  o[t + 512] = (v2 - mean) * rs * g[t + 512] + be[t + 512];
}

// =====================================================================
extern "C" void kernel_launch(void* const* d_in, const int* in_sizes, int n_in,
                              void* d_out, int out_size, void* d_ws, size_t ws_size,
                              hipStream_t stream) {
  static const int N_[5]  = {256, 1024, 4096, 16384, 65536};
  static const int CN_[5] = {512, 384, 192, 96, 48};
  static const int CF_[5] = {512, 896, 1088, 1184, 1232};
  static const int KP_[5] = {512, 896, 1088, 1216, 1280};   // CF rounded to 64
  static const int NC_[5] = {1, 1, 2, 2, 4};                // point-chunks (no atomics)

  const float* x[5]; const int* p2s[5]; const float* W[5];
  const float* bias[5]; const float* g[5]; const float* be[5];
  for (int i = 0; i < 5; i++) {
    x[i]    = (const float*)d_in[6 * i + 0];
    p2s[i]  = (const int*)  d_in[6 * i + 1];
    W[i]    = (const float*)d_in[6 * i + 2];
    bias[i] = (const float*)d_in[6 * i + 3];
    g[i]    = (const float*)d_in[6 * i + 4];
    be[i]   = (const float*)d_in[6 * i + 5];
  }
  const int* inv[5] = {nullptr, (const int*)d_in[30], (const int*)d_in[31],
                       (const int*)d_in[32], (const int*)d_in[33]};

  int*   wsi = (int*)d_ws;
  float* wsf = (float*)d_ws;
  unsigned short* wsu = (unsigned short*)d_ws;

  // ---- workspace layout (round-8 verified chain, XB overlay removed) ----
  // f32-slot offsets:
  const int CNT = 0, CUR = 5120, OFS = 10240, SCL = 15360;
  static const int PT[5]   = {20480, 20992, 23040, 31232, 64000};          // end 195072
  const int CI20 = 195072, CI31 = 203264, CI30 = 236032;
  const int CI42 = 268800, CI41 = 399872, CI40 = 530944;                   // end 662016 (contiguous)
  static const int SG01[2] = {662016, 1186304};                            // fp32 seg lvl0/1, end 2103808
  // u16 offsets:
  static const int PPu[5]  = {0, 0, 4207616, 6435840, 8860672};            // bf16 partials lvl2/3/4, end 13906944
  static const int SBu[5]  = {13906944, 14431232, 15348736, 16462848, 17708032}; // end 19018752 (38.04 MB proven)
  // overlays (dead regions, strict within-call stream order):
  static const int WTu[5]  = {1324032, 1717248, 2405376, 3240960, 4174848};// over SG01/PP2-head (live conv_wt->gemm)
  const int PROJ = 2578944;                                                // f32 over PP2-tail/PP3/PP4 (live gemm->ln)

  hipMemsetAsync(wsi + CNT, 0, (size_t)10240 * 4, stream);   // cnt + cur only

  auto nb = [](int tot) { return (tot + 255) / 256; };

  compose2_k<<<nb(2 * 4096),  256, 0, stream>>>(wsi + CI20, inv[2], inv[1], 2 * 4096);
  compose3_k<<<nb(2 * 16384), 256, 0, stream>>>(wsi + CI31, wsi + CI30, inv[3], inv[2], inv[1], 2 * 16384);
  compose4_k<<<nb(2 * 65536), 256, 0, stream>>>(wsi + CI42, wsi + CI41, wsi + CI40,
                                                inv[4], inv[3], inv[2], inv[1], 2 * 65536);

  for (int i = 0; i < 5; i++)
    hist_k<<<nb(2 * N_[i]), 256, 0, stream>>>(wsi + CNT + i * 1024, p2s[i], N_[i], 2 * N_[i]);

  scan_k<<<10, 512, 0, stream>>>(wsi + CNT, wsi + OFS, wsf + SCL);

  for (int i = 0; i < 5; i++)
    scat_k<<<nb(2 * N_[i]), 256, 0, stream>>>(wsi + PT[i], wsi + CUR + i * 1024,
                                              wsi + OFS + i * 1024, p2s[i], N_[i], 2 * N_[i]);

  const int* cimap[5][5] = {};
  cimap[1][0] = inv[1];
  cimap[2][1] = inv[2]; cimap[2][0] = wsi + CI20;
  cimap[3][2] = inv[3]; cimap[3][1] = wsi + CI31; cimap[3][0] = wsi + CI30;
  cimap[4][3] = inv[4]; cimap[4][2] = wsi + CI42; cimap[4][1] = wsi + CI41; cimap[4][0] = wsi + CI40;

  int offs[5][5] = {};
  for (int i = 1; i < 5; i++)
    for (int j = i - 1; j >= 0; j--) offs[i][j] = CN_[i] + offs[i - 1][j];

  for (int i = 0; i < 5; i++) {
    RedArgs ra{};
    int d = 0;
    for (int j = i; j >= 0; j--) {
      ra.x[d]   = x[j];
      ra.ci[d]  = (j == i) ? nullptr : cimap[i][j];
      ra.Nj[d]  = N_[j];
      ra.CN[d]  = CN_[j];
      ra.OFF[d] = offs[i][j];
      d++;
    }
    ra.nb = d; ra.N = N_[i]; ra.CF = CF_[i];
    if (i <= 1)
      reduce2_k<<<1024, 256, 0, stream>>>(ra, wsi + PT[i], wsi + CNT + i * 1024,
                                          wsi + OFS + i * 1024, wsf + SG01[i]);
    else
      reduce_sl_k<<<dim3(8, 1024, NC_[i]), 64, 0, stream>>>(ra, wsi + PT[i], wsi + CNT + i * 1024,
                                                            wsi + OFS + i * 1024,
                                                            wsu + PPu[i], NC_[i]);
  }

  // combine partials -> scaled bf16 seg (swizzled, K-padded)
  CsArgs ca{};
  ca.sg[0] = wsf + SG01[0]; ca.sg[1] = wsf + SG01[1];
  for (int i = 0; i < 5; i++) {
    ca.pp[i] = (i >= 2) ? (wsu + PPu[i]) : nullptr;
    ca.sb[i] = wsu + SBu[i];
    ca.CF[i] = CF_[i]; ca.KP[i] = KP_[i]; ca.NC[i] = NC_[i];
  }
  ca.scl = wsf + SCL;
  conv_seg_k<<<5120, 256, 0, stream>>>(ca);

  // W -> bf16 transposed (over dead SG01/PP2-head; AFTER conv_seg)
  CwArgs cw{};
  for (int i = 0; i < 5; i++) { cw.w[i] = W[i]; cw.wt[i] = wsu + WTu[i]; cw.CF[i] = CF_[i]; cw.KP[i] = KP_[i]; }
  conv_wt_k<<<dim3(480, 5), 256, 0, stream>>>(cw);

  // MFMA GEMM (writes PROJ over dead partials region)
  G2Args ga{};
  for (int i = 0; i < 5; i++) {
    ga.sb[i] = wsu + SBu[i]; ga.wt[i] = wsu + WTu[i]; ga.bias[i] = bias[i];
    ga.KP[i] = KP_[i]; ga.KIT[i] = KP_[i] >> 6;
  }
  ga.proj = wsf + PROJ;
  gemm2_k<<<dim3(12, 8, 5), 256, 0, stream>>>(ga);

  LnArgs la{};
  for (int i = 0; i < 5; i++) { la.g[i] = g[i]; la.be[i] = be[i]; }
  ln_k<<<5120, 256, 0, stream>>>(la, wsf + PROJ, (float*)d_out);
}

// Round 10
// 189.931 us; speedup vs baseline: 3.0064x; 3.0064x over previous
//
#include <hip/hip_runtime.h>
#include <hip/hip_bf16.h>

#define NSEG 512
#define HID 768

typedef __attribute__((ext_vector_type(8))) short s16x8;
typedef __attribute__((ext_vector_type(8))) unsigned short u16x8;
typedef __attribute__((ext_vector_type(4))) unsigned short u16x4;
typedef __attribute__((ext_vector_type(4))) float f32x4;

__device__ __forceinline__ unsigned short f2bf(float x) {
  unsigned u = __builtin_bit_cast(unsigned, x);
  unsigned r = (u + 0x7fff + ((u >> 16) & 1)) >> 16;   // RNE
  return (unsigned short)r;
}

__device__ __forceinline__ float bf2f(unsigned short h) {
  unsigned u = ((unsigned)h) << 16;
  return __builtin_bit_cast(float, u);
}

__device__ __forceinline__ void gl_lds16(const void* g, void* l) {
  __builtin_amdgcn_global_load_lds(
      (const __attribute__((address_space(1))) unsigned*)g,
      (__attribute__((address_space(3))) unsigned*)l, 16, 0, 0);
}

// ---------------- fused compose (all chains) + histogram (all levels) ----------------
// thread ranges: [0,8192) c20 | [8192,40960) c31,c30 | [40960,172032) c42,c41,c40
//                [172032,346624) histogram
struct PreArgs {
  const int *inv1, *inv2, *inv3, *inv4;
  int *c20, *c31, *c30, *c42, *c41, *c40;
  const int* p2s[5];
  int* cnt;
};

__device__ __forceinline__ bool lvl_decode(int t, int& lvl, int& u, int& N) {
  if      (t < 512)    { lvl = 0; u = t;          N = 256; }
  else if (t < 2560)   { lvl = 1; u = t - 512;    N = 1024; }
  else if (t < 10752)  { lvl = 2; u = t - 2560;   N = 4096; }
  else if (t < 43520)  { lvl = 3; u = t - 10752;  N = 16384; }
  else if (t < 174592) { lvl = 4; u = t - 43520;  N = 65536; }
  else return false;
  return true;
}

__global__ __launch_bounds__(256)
void pre_k(PreArgs a) {
  int t = blockIdx.x * 256 + threadIdx.x;
  if (t < 8192) {
    int b = (t >= 4096);
    a.c20[t] = a.inv1[b * 1024 + a.inv2[t]];
  } else if (t < 40960) {
    int u = t - 8192;
    int b = (u >= 16384);
    int n2 = a.inv3[u];
    int n1 = a.inv2[b * 4096 + n2]; a.c31[u] = n1;
    a.c30[u] = a.inv1[b * 1024 + n1];
  } else if (t < 172032) {
    int u = t - 40960;
    int b = (u >= 65536);
    int n3 = a.inv4[u];
    int n2 = a.inv3[b * 16384 + n3]; a.c42[u] = n2;
    int n1 = a.inv2[b * 4096 + n2];  a.c41[u] = n1;
    a.c40[u] = a.inv1[b * 1024 + n1];
  } else {
    int u0 = t - 172032;
    int lvl, u, N;
    if (!lvl_decode(u0, lvl, u, N)) return;
    int b = (u >= N);
    atomicAdd(&a.cnt[lvl * 1024 + b * NSEG + a.p2s[lvl][u]], 1);
  }
}

// ---------------- scan + 1/m ----------------
__global__ __launch_bounds__(512)
void scan_k(const int* __restrict__ cnt, int* __restrict__ off, float* __restrict__ scl) {
  __shared__ int sm[NSEG];
  int base = blockIdx.x * NSEG;
  int t = threadIdx.x;
  int v = cnt[base + t];
  sm[t] = v;
  __syncthreads();
  for (int d = 1; d < NSEG; d <<= 1) {
    int u = (t >= d) ? sm[t - d] : 0;
    __syncthreads();
    sm[t] += u;
    __syncthreads();
  }
  off[base + t] = sm[t] - v;
  scl[base + t] = 1.0f / (float)(v > 0 ? v : 1);
}

// ---------------- fused scatter (all levels) ----------------
struct ScArgs { const int* p2s[5]; int* pt[5]; int* cur; const int* off; };

__global__ __launch_bounds__(256)
void scat_all_k(ScArgs a) {
  int t = blockIdx.x * 256 + threadIdx.x;
  int lvl, u, N;
  if (!lvl_decode(t, lvl, u, N)) return;
  int b = (u >= N);
  int n = u - b * N;
  int idx = lvl * 1024 + b * NSEG + a.p2s[lvl][u];
  int pos = a.off[idx] + atomicAdd(&a.cur[idx], 1);
  a.pt[lvl][b * N + pos] = n;
}

// ---------------- mega reduce: all levels, one launch, fp32 gathers ----------------
// block ranges: lvl0 [0,1024) lvl1 [1024,2048) lvl2 [2048,4096) lvl3 [4096,6144) lvl4 [6144,10240)
// lvl0/1: direct fp32 seg write (incl. m==0 zero-fill). lvl2-4: chunked bf16 partials.
struct RedAll {
  const float* x[5][5];
  const int*   ci[5][5];
  int Njl[5][5], CN[5][5], colOFF[5][5];
  int nb[5], N[5], CF[5], nchunk[5];
  const int* pt[5]; const int* cnt[5]; const int* segoff[5];
  float* seg01[2];
  unsigned short* part[5];
};

__global__ __launch_bounds__(256)
void reduce3_k(RedAll A) {
  int gb = blockIdx.x;
  int lvl, lb;
  if      (gb < 1024) { lvl = 0; lb = gb; }
  else if (gb < 2048) { lvl = 1; lb = gb - 1024; }
  else if (gb < 4096) { lvl = 2; lb = gb - 2048; }
  else if (gb < 6144) { lvl = 3; lb = gb - 4096; }
  else                { lvl = 4; lb = gb - 6144; }
  int chunk = lb >> 10;
  int bs    = lb & 1023;
  int b     = bs >> 9;
  int t     = threadIdx.x;
  int m     = A.cnt[lvl][bs];
  int CF    = A.CF[lvl];
  int nb    = A.nb[lvl];
  int N     = A.N[lvl];

  const float* xs[2]; const int* cim[2]; int str[2]; bool val[2];
#pragma unroll
  for (int k = 0; k < 2; k++) {
    int c4 = (t + k * 256) * 4;
    val[k] = c4 < CF;
    xs[k] = nullptr; cim[k] = nullptr; str[k] = 1;
    if (val[k]) {
      int j = 0;
      while (j < nb - 1 && !(c4 >= A.colOFF[lvl][j] && c4 < A.colOFF[lvl][j] + A.CN[lvl][j])) j++;
      xs[k]  = A.x[lvl][j] + (size_t)b * A.Njl[lvl][j] * A.CN[lvl][j] + (c4 - A.colOFF[lvl][j]);
      cim[k] = A.ci[lvl][j] ? (A.ci[lvl][j] + (size_t)b * N) : nullptr;
      str[k] = A.CN[lvl][j];
    }
  }

  bool direct = (lvl <= 1);
  int start = 0, end = m;
  if (!direct) {
    int nch = A.nchunk[lvl];
    int cs = (m + nch - 1) / nch;
    start = chunk * cs;
    end = min(m, start + cs);
  } else if (m == 0) {
    float* so = A.seg01[lvl] + (size_t)bs * CF;
#pragma unroll
    for (int k = 0; k < 2; k++)
      if (val[k]) *(float4*)(so + (t + k * 256) * 4) = make_float4(0.f, 0.f, 0.f, 0.f);
    return;
  }

  float ax[2][4] = {};
  if (start < end) {
    const int* pl = A.pt[lvl] + (size_t)b * N + A.segoff[lvl][bs];
    int p = start;
    for (; p + 4 <= end; p += 4) {
      int n0 = pl[p], n1 = pl[p + 1], n2 = pl[p + 2], n3 = pl[p + 3];
#pragma unroll
      for (int k = 0; k < 2; k++) if (val[k]) {
        int r0 = cim[k] ? cim[k][n0] : n0;
        int r1 = cim[k] ? cim[k][n1] : n1;
        int r2 = cim[k] ? cim[k][n2] : n2;
        int r3 = cim[k] ? cim[k][n3] : n3;
        float4 v0 = *(const float4*)(xs[k] + (size_t)r0 * str[k]);
        float4 v1 = *(const float4*)(xs[k] + (size_t)r1 * str[k]);
        float4 v2 = *(const float4*)(xs[k] + (size_t)r2 * str[k]);
        float4 v3 = *(const float4*)(xs[k] + (size_t)r3 * str[k]);
        ax[k][0] += (v0.x + v1.x) + (v2.x + v3.x);
        ax[k][1] += (v0.y + v1.y) + (v2.y + v3.y);
        ax[k][2] += (v0.z + v1.z) + (v2.z + v3.z);
        ax[k][3] += (v0.w + v1.w) + (v2.w + v3.w);
      }
    }
    for (; p < end; p++) {
      int n0 = pl[p];
#pragma unroll
      for (int k = 0; k < 2; k++) if (val[k]) {
        int r0 = cim[k] ? cim[k][n0] : n0;
        float4 v0 = *(const float4*)(xs[k] + (size_t)r0 * str[k]);
        ax[k][0] += v0.x; ax[k][1] += v0.y; ax[k][2] += v0.z; ax[k][3] += v0.w;
      }
    }
  }

  if (direct) {
    float* so = A.seg01[lvl] + (size_t)bs * CF;
#pragma unroll
    for (int k = 0; k < 2; k++) if (val[k]) {
      int c4 = (t + k * 256) * 4;
      *(float4*)(so + c4) = make_float4(ax[k][0], ax[k][1], ax[k][2], ax[k][3]);
    }
  } else {
    unsigned short* po = A.part[lvl] + ((size_t)chunk * 1024 + bs) * CF;
#pragma unroll
    for (int k = 0; k < 2; k++) if (val[k]) {
      int c4 = (t + k * 256) * 4;
      u16x4 o = {f2bf(ax[k][0]), f2bf(ax[k][1]), f2bf(ax[k][2]), f2bf(ax[k][3])};
      *(u16x4*)(po + c4) = o;
    }
  }
}

// ---------------- combine partials + scale + bf16 + chunk-swizzle + K-pad ----------------
struct CsArgs {
  const float* sg[2];              // levels 0,1: fp32 seg sums
  const unsigned short* pp[5];     // levels 2..4: bf16 partials [NC][1024][CF]
  unsigned short* sb[5];
  const float* scl;
  int CF[5]; int KP[5]; int NC[5];
};

__global__ __launch_bounds__(256)
void conv_seg_k(CsArgs a) {
  int row = blockIdx.x;            // 0..5119
  int lvl = row >> 10;
  int rl  = row & 1023;
  int CF = a.CF[lvl], KP = a.KP[lvl];
  int c = threadIdx.x;
  if (c >= (KP >> 3)) return;
  float s = a.scl[row];
  int w = c & 7, blk = c >> 3;
  int k0 = blk * 64 + ((w ^ (rl & 7)) << 3);
  u16x8 o = {0, 0, 0, 0, 0, 0, 0, 0};
  if (k0 < CF) {
    float acc[8] = {};
    if (lvl <= 1) {
      const float* src = a.sg[lvl] + (size_t)rl * CF + k0;
      float4 v0 = *(const float4*)src;
      float4 v1 = *(const float4*)(src + 4);
      acc[0] = v0.x; acc[1] = v0.y; acc[2] = v0.z; acc[3] = v0.w;
      acc[4] = v1.x; acc[5] = v1.y; acc[6] = v1.z; acc[7] = v1.w;
    } else {
      int nc = a.NC[lvl];
      const unsigned short* base = a.pp[lvl] + (size_t)rl * CF + k0;
      for (int n = 0; n < nc; n++) {
        u16x8 v = *(const u16x8*)(base + (size_t)n * 1024 * CF);
#pragma unroll
        for (int e = 0; e < 8; e++) acc[e] += bf2f(v[e]);
      }
    }
#pragma unroll
    for (int e = 0; e < 8; e++) o[e] = f2bf(acc[e] * s);
  }
  *(u16x8*)(a.sb[lvl] + (size_t)rl * KP + c * 8) = o;
}

// ---------------- W [CF][768] fp32 -> Wt [768][KP] bf16 transposed+swizzled ----------------
struct CwArgs { const float* w[5]; unsigned short* wt[5]; int CF[5]; int KP[5]; };

__global__ __launch_bounds__(256)
void conv_wt_k(CwArgs a) {
  int lvl = blockIdx.y;
  int KP = a.KP[lvl], CF = a.CF[lvl];
  int idx = blockIdx.x * 256 + threadIdx.x;
  if (idx >= 768 * (KP >> 3)) return;
  int c = idx / 768;
  int n = idx - c * 768;
  int w = c & 7, blk = c >> 3;
  int k0 = blk * 64 + ((w ^ (n & 7)) << 3);
  u16x8 o = {0, 0, 0, 0, 0, 0, 0, 0};
  if (k0 < CF) {
    const float* src = a.w[lvl] + (size_t)k0 * HID + n;
#pragma unroll
    for (int e = 0; e < 8; e++) o[e] = f2bf(src[(size_t)e * HID]);
  }
  *(u16x8*)(a.wt[lvl] + (size_t)n * KP + c * 8) = o;
}

// ---------------- bf16 MFMA GEMM: proj = segbf @ Wt^T + bias ----------------
struct G2Args {
  const unsigned short* sb[5];
  const unsigned short* wt[5];
  const float* bias[5];
  float* proj;
  int KP[5];
  int KIT[5];
};

__global__ __launch_bounds__(256)
void gemm2_k(G2Args g) {
  int lvl = blockIdx.z;
  int n0 = blockIdx.x * 64;
  int m0 = blockIdx.y * 128;
  const char* A = (const char*)g.sb[lvl];
  const char* Bw = (const char*)g.wt[lvl];
  int KP = g.KP[lvl];
  int KIT = g.KIT[lvl];

  __shared__ char smem[49152];     // 2 x (16KB A + 8KB B)

  int t = threadIdx.x;
  int lane = t & 63;
  int w = t >> 6;
  int wm = w >> 1, wn = w & 1;

  f32x4 acc[4][2] = {};

  int rowb = t >> 3;
  int colb = (t & 7) * 16;

  auto stg = [&](int buf, int it) {
    char* base = smem + buf * 24576;
#pragma unroll
    for (int j = 0; j < 4; j++) {
      int row = j * 32 + rowb;
      gl_lds16(A + (size_t)(m0 + row) * (KP * 2) + it * 128 + colb,
               base + j * 4096 + t * 16);
    }
#pragma unroll
    for (int j = 0; j < 2; j++) {
      int row = j * 32 + rowb;
      gl_lds16(Bw + (size_t)(n0 + row) * (KP * 2) + it * 128 + colb,
               base + 16384 + j * 4096 + t * 16);
    }
  };

  int r15 = lane & 15, hi = lane >> 4, sx = (lane & 7) << 4;

  stg(0, 0);
  int cur = 0;
  for (int it = 0; it < KIT; ++it) {
    __syncthreads();
    if (it + 1 < KIT) stg(cur ^ 1, it + 1);
    const char* base = smem + cur * 24576;
    s16x8 af[2][4]; s16x8 bf2v[2][2];
#pragma unroll
    for (int s = 0; s < 2; s++) {
      int cb = (s * 64 + hi * 16) ^ sx;
#pragma unroll
      for (int fm = 0; fm < 4; fm++) {
        int row = wm * 64 + fm * 16 + r15;
        af[s][fm] = *(const s16x8*)(base + row * 128 + cb);
      }
#pragma unroll
      for (int fn = 0; fn < 2; fn++) {
        int row = wn * 32 + fn * 16 + r15;
        bf2v[s][fn] = *(const s16x8*)(base + 16384 + row * 128 + cb);
      }
    }
#pragma unroll
    for (int s = 0; s < 2; s++)
#pragma unroll
      for (int fm = 0; fm < 4; fm++)
#pragma unroll
        for (int fn = 0; fn < 2; fn++)
          acc[fm][fn] = __builtin_amdgcn_mfma_f32_16x16x32_bf16(af[s][fm], bf2v[s][fn], acc[fm][fn], 0, 0, 0);
    cur ^= 1;
  }

  const float* bias = g.bias[lvl];
  float* proj = g.proj + ((size_t)lvl * 1024 + m0) * HID;
#pragma unroll
  for (int fm = 0; fm < 4; fm++)
#pragma unroll
    for (int fn = 0; fn < 2; fn++) {
      int col = n0 + wn * 32 + fn * 16 + r15;
      int rb = wm * 64 + fm * 16 + hi * 4;
      float bi = bias[col];
      f32x4 v = acc[fm][fn];
#pragma unroll
      for (int r = 0; r < 4; r++)
        proj[(size_t)(rb + r) * HID + col] = v[r] + bi;
    }
}

// ---------------- LayerNorm over HID=768 (fp32 in/out) ----------------
struct LnArgs { const float* g[5]; const float* be[5]; };

__global__ __launch_bounds__(256)
void ln_k(LnArgs la, const float* __restrict__ proj, float* __restrict__ out) {
  int row = blockIdx.x;
  int lvl = row >> 10;
  const float* x = proj + (size_t)row * HID;
  int t = threadIdx.x;
  float v0 = x[t], v1 = x[t + 256], v2 = x[t + 512];
  float s = v0 + v1 + v2;
  float q = v0 * v0 + v1 * v1 + v2 * v2;
#pragma unroll
  for (int d = 32; d >= 1; d >>= 1) { s += __shfl_down(s, d); q += __shfl_down(q, d); }
  __shared__ float ps[4], pq[4];
  int w = t >> 6;
  if ((t & 63) == 0) { ps[w] = s; pq[w] = q; }
  __syncthreads();
  float S = ps[0] + ps[1] + ps[2] + ps[3];
  float Q = pq[0] + pq[1] + pq[2] + pq[3];
  float mean = S * (1.0f / HID);
  float var  = Q * (1.0f / HID) - mean * mean;
  float rs   = rsqrtf(var + 1e-5f);
  const float* g  = la.g[lvl];
  const float* be = la.be[lvl];
  float* o = out + (size_t)row * HID;
  o[t]       = (v0 - mean) * rs * g[t]       + be[t];
  o[t + 256] = (v1 - mean) * rs * g[t + 256] + be[t + 256];
  o[t + 512] = (v2 - mean) * rs * g[t + 512] + be[t + 512];
}

// =====================================================================
extern "C" void kernel_launch(void* const* d_in, const int* in_sizes, int n_in,
                              void* d_out, int out_size, void* d_ws, size_t ws_size,
                              hipStream_t stream) {
  static const int N_[5]  = {256, 1024, 4096, 16384, 65536};
  static const int CN_[5] = {512, 384, 192, 96, 48};
  static const int CF_[5] = {512, 896, 1088, 1184, 1232};
  static const int KP_[5] = {512, 896, 1088, 1216, 1280};   // CF rounded to 64
  static const int NC_[5] = {1, 1, 2, 2, 4};                // point-chunks (no atomics)

  const float* x[5]; const int* p2s[5]; const float* W[5];
  const float* bias[5]; const float* g[5]; const float* be[5];
  for (int i = 0; i < 5; i++) {
    x[i]    = (const float*)d_in[6 * i + 0];
    p2s[i]  = (const int*)  d_in[6 * i + 1];
    W[i]    = (const float*)d_in[6 * i + 2];
    bias[i] = (const float*)d_in[6 * i + 3];
    g[i]    = (const float*)d_in[6 * i + 4];
    be[i]   = (const float*)d_in[6 * i + 5];
  }
  const int* inv[5] = {nullptr, (const int*)d_in[30], (const int*)d_in[31],
                       (const int*)d_in[32], (const int*)d_in[33]};

  int*   wsi = (int*)d_ws;
  float* wsf = (float*)d_ws;
  unsigned short* wsu = (unsigned short*)d_ws;

  // ---- workspace layout (r5/r8-proven chain, verified contiguous) ----
  // f32-slot offsets:
  const int CNT = 0, CUR = 5120, OFS = 10240, SCL = 15360;
  static const int PT[5]   = {20480, 20992, 23040, 31232, 64000};          // end 195072
  const int CI20 = 195072, CI31 = 203264, CI30 = 236032;                   // +8192,+32768,+32768
  const int CI42 = 268800, CI41 = 399872, CI40 = 530944;                   // +131072 each -> end 662016
  static const int SG01[2] = {662016, 1186304};                            // fp32 seg lvl0/1, end 2103808
  // u16 offsets:
  static const int PPu[5]  = {0, 0, 4207616, 6435840, 8860672};            // bf16 partials lvl2/3/4, end 13906944
  static const int SBu[5]  = {13906944, 14431232, 15348736, 16462848, 17708032}; // end 19018752 (38.04 MB proven)
  // overlays (dead regions, strict within-call stream order):
  static const int WTu[5]  = {1324032, 1717248, 2405376, 3240960, 4174848};// over SG01/PP2-head (live conv_wt->gemm)
  const int PROJ = 2578944;                                                // f32 over PP2-tail/PP3/PP4 (live gemm->ln)

  hipMemsetAsync(wsi + CNT, 0, (size_t)10240 * 4, stream);   // cnt + cur only

  // fused compose + histogram
  PreArgs pa{inv[1], inv[2], inv[3], inv[4],
             wsi + CI20, wsi + CI31, wsi + CI30, wsi + CI42, wsi + CI41, wsi + CI40,
             {}, wsi + CNT};
  for (int i = 0; i < 5; i++) pa.p2s[i] = p2s[i];
  pre_k<<<1354, 256, 0, stream>>>(pa);         // 346624 threads

  scan_k<<<10, 512, 0, stream>>>(wsi + CNT, wsi + OFS, wsf + SCL);

  ScArgs sc{};
  for (int i = 0; i < 5; i++) { sc.p2s[i] = p2s[i]; sc.pt[i] = wsi + PT[i]; }
  sc.cur = wsi + CUR; sc.off = wsi + OFS;
  scat_all_k<<<682, 256, 0, stream>>>(sc);

  // mega reduce (all 5 levels, one launch)
  const int* cimap[5][5] = {};
  cimap[1][0] = inv[1];
  cimap[2][1] = inv[2]; cimap[2][0] = wsi + CI20;
  cimap[3][2] = inv[3]; cimap[3][1] = wsi + CI31; cimap[3][0] = wsi + CI30;
  cimap[4][3] = inv[4]; cimap[4][2] = wsi + CI42; cimap[4][1] = wsi + CI41; cimap[4][0] = wsi + CI40;

  int offs[5][5] = {};
  for (int i = 1; i < 5; i++)
    for (int j = i - 1; j >= 0; j--) offs[i][j] = CN_[i] + offs[i - 1][j];

  RedAll ra{};
  for (int i = 0; i < 5; i++) {
    int d = 0;
    for (int j = i; j >= 0; j--) {
      ra.x[i][d]      = x[j];
      ra.ci[i][d]     = (j == i) ? nullptr : cimap[i][j];
      ra.Njl[i][d]    = N_[j];
      ra.CN[i][d]     = CN_[j];
      ra.colOFF[i][d] = offs[i][j];
      d++;
    }
    ra.nb[i] = d; ra.N[i] = N_[i]; ra.CF[i] = CF_[i]; ra.nchunk[i] = NC_[i];
    ra.pt[i] = wsi + PT[i]; ra.cnt[i] = wsi + CNT + i * 1024;
    ra.segoff[i] = wsi + OFS + i * 1024;
    ra.part[i] = (i >= 2) ? (wsu + PPu[i]) : nullptr;
  }
  ra.seg01[0] = wsf + SG01[0]; ra.seg01[1] = wsf + SG01[1];
  reduce3_k<<<10240, 256, 0, stream>>>(ra);    // 1024+1024+2048+2048+4096

  // combine partials -> scaled bf16 seg (swizzled, K-padded)
  CsArgs ca{};
  ca.sg[0] = wsf + SG01[0]; ca.sg[1] = wsf + SG01[1];
  for (int i = 0; i < 5; i++) {
    ca.pp[i] = (i >= 2) ? (wsu + PPu[i]) : nullptr;
    ca.sb[i] = wsu + SBu[i];
    ca.CF[i] = CF_[i]; ca.KP[i] = KP_[i]; ca.NC[i] = NC_[i];
  }
  ca.scl = wsf + SCL;
  conv_seg_k<<<5120, 256, 0, stream>>>(ca);

  // W -> bf16 transposed (over dead SG01/PP2-head; AFTER conv_seg)
  CwArgs cw{};
  for (int i = 0; i < 5; i++) { cw.w[i] = W[i]; cw.wt[i] = wsu + WTu[i]; cw.CF[i] = CF_[i]; cw.KP[i] = KP_[i]; }
  conv_wt_k<<<dim3(480, 5), 256, 0, stream>>>(cw);

  // MFMA GEMM (writes PROJ over dead partials region)
  G2Args ga{};
  for (int i = 0; i < 5; i++) {
    ga.sb[i] = wsu + SBu[i]; ga.wt[i] = wsu + WTu[i]; ga.bias[i] = bias[i];
    ga.KP[i] = KP_[i]; ga.KIT[i] = KP_[i] >> 6;
  }
  ga.proj = wsf + PROJ;
  gemm2_k<<<dim3(12, 8, 5), 256, 0, stream>>>(ga);

  LnArgs la{};
  for (int i = 0; i < 5; i++) { la.g[i] = g[i]; la.be[i] = be[i]; }
  ln_k<<<5120, 256, 0, stream>>>(la, wsf + PROJ, (float*)d_out);
}

// Round 11
// 171.429 us; speedup vs baseline: 3.3309x; 1.1079x over previous
//
#include <hip/hip_runtime.h>
#include <hip/hip_bf16.h>

#define NSEG 512
#define HID 768

typedef __attribute__((ext_vector_type(8))) short s16x8;
typedef __attribute__((ext_vector_type(8))) unsigned short u16x8;
typedef __attribute__((ext_vector_type(4))) unsigned short u16x4;
typedef __attribute__((ext_vector_type(4))) float f32x4;

__device__ __forceinline__ unsigned short f2bf(float x) {
  unsigned u = __builtin_bit_cast(unsigned, x);
  unsigned r = (u + 0x7fff + ((u >> 16) & 1)) >> 16;   // RNE
  return (unsigned short)r;
}

__device__ __forceinline__ float bf2f(unsigned short h) {
  unsigned u = ((unsigned)h) << 16;
  return __builtin_bit_cast(float, u);
}

__device__ __forceinline__ void gl_lds16(const void* g, void* l) {
  __builtin_amdgcn_global_load_lds(
      (const __attribute__((address_space(1))) unsigned*)g,
      (__attribute__((address_space(3))) unsigned*)l, 16, 0, 0);
}

// ---------------- fused compose (all chains) + histogram (all levels) ----------------
struct PreArgs {
  const int *inv1, *inv2, *inv3, *inv4;
  int *c20, *c31, *c30, *c42, *c41, *c40;
  const int* p2s[5];
  int* cnt;
};

__device__ __forceinline__ bool lvl_decode(int t, int& lvl, int& u, int& N) {
  if      (t < 512)    { lvl = 0; u = t;          N = 256; }
  else if (t < 2560)   { lvl = 1; u = t - 512;    N = 1024; }
  else if (t < 10752)  { lvl = 2; u = t - 2560;   N = 4096; }
  else if (t < 43520)  { lvl = 3; u = t - 10752;  N = 16384; }
  else if (t < 174592) { lvl = 4; u = t - 43520;  N = 65536; }
  else return false;
  return true;
}

__global__ __launch_bounds__(256)
void pre_k(PreArgs a) {
  int t = blockIdx.x * 256 + threadIdx.x;
  if (t < 8192) {
    int b = (t >= 4096);
    a.c20[t] = a.inv1[b * 1024 + a.inv2[t]];
  } else if (t < 40960) {
    int u = t - 8192;
    int b = (u >= 16384);
    int n2 = a.inv3[u];
    int n1 = a.inv2[b * 4096 + n2]; a.c31[u] = n1;
    a.c30[u] = a.inv1[b * 1024 + n1];
  } else if (t < 172032) {
    int u = t - 40960;
    int b = (u >= 65536);
    int n3 = a.inv4[u];
    int n2 = a.inv3[b * 16384 + n3]; a.c42[u] = n2;
    int n1 = a.inv2[b * 4096 + n2];  a.c41[u] = n1;
    a.c40[u] = a.inv1[b * 1024 + n1];
  } else {
    int u0 = t - 172032;
    int lvl, u, N;
    if (!lvl_decode(u0, lvl, u, N)) return;
    int b = (u >= N);
    atomicAdd(&a.cnt[lvl * 1024 + b * NSEG + a.p2s[lvl][u]], 1);
  }
}

// ---------------- scan + 1/m ----------------
__global__ __launch_bounds__(512)
void scan_k(const int* __restrict__ cnt, int* __restrict__ off, float* __restrict__ scl) {
  __shared__ int sm[NSEG];
  int base = blockIdx.x * NSEG;
  int t = threadIdx.x;
  int v = cnt[base + t];
  sm[t] = v;
  __syncthreads();
  for (int d = 1; d < NSEG; d <<= 1) {
    int u = (t >= d) ? sm[t - d] : 0;
    __syncthreads();
    sm[t] += u;
    __syncthreads();
  }
  off[base + t] = sm[t] - v;
  scl[base + t] = 1.0f / (float)(v > 0 ? v : 1);
}

// ---------------- fused scatter (all levels) ----------------
struct ScArgs { const int* p2s[5]; int* pt[5]; int* cur; const int* off; };

__global__ __launch_bounds__(256)
void scat_all_k(ScArgs a) {
  int t = blockIdx.x * 256 + threadIdx.x;
  int lvl, u, N;
  if (!lvl_decode(t, lvl, u, N)) return;
  int b = (u >= N);
  int n = u - b * N;
  int idx = lvl * 1024 + b * NSEG + a.p2s[lvl][u];
  int pos = a.off[idx] + atomicAdd(&a.cur[idx], 1);
  a.pt[lvl][b * N + pos] = n;
}

// ---------------- mega reduce: all levels, one launch, fp32 gathers, 8-pt unroll ----------------
struct RedAll {
  const float* x[5][5];
  const int*   ci[5][5];
  int Njl[5][5], CN[5][5], colOFF[5][5];
  int nb[5], N[5], CF[5], nchunk[5];
  const int* pt[5]; const int* cnt[5]; const int* segoff[5];
  float* seg01[2];
  unsigned short* part[5];
};

__global__ __launch_bounds__(256)
void reduce3_k(RedAll A) {
  int gb = blockIdx.x;
  int lvl, lb;
  if      (gb < 1024) { lvl = 0; lb = gb; }
  else if (gb < 2048) { lvl = 1; lb = gb - 1024; }
  else if (gb < 4096) { lvl = 2; lb = gb - 2048; }
  else if (gb < 6144) { lvl = 3; lb = gb - 4096; }
  else                { lvl = 4; lb = gb - 6144; }
  int chunk = lb >> 10;
  int bs    = lb & 1023;
  int b     = bs >> 9;
  int t     = threadIdx.x;
  int m     = A.cnt[lvl][bs];
  int CF    = A.CF[lvl];
  int nb    = A.nb[lvl];
  int N     = A.N[lvl];

  const float* xs[2]; const int* cim[2]; int str[2]; bool val[2];
#pragma unroll
  for (int k = 0; k < 2; k++) {
    int c4 = (t + k * 256) * 4;
    val[k] = c4 < CF;
    xs[k] = nullptr; cim[k] = nullptr; str[k] = 1;
    if (val[k]) {
      int j = 0;
      while (j < nb - 1 && !(c4 >= A.colOFF[lvl][j] && c4 < A.colOFF[lvl][j] + A.CN[lvl][j])) j++;
      xs[k]  = A.x[lvl][j] + (size_t)b * A.Njl[lvl][j] * A.CN[lvl][j] + (c4 - A.colOFF[lvl][j]);
      cim[k] = A.ci[lvl][j] ? (A.ci[lvl][j] + (size_t)b * N) : nullptr;
      str[k] = A.CN[lvl][j];
    }
  }

  bool direct = (lvl <= 1);
  int start = 0, end = m;
  if (!direct) {
    int nch = A.nchunk[lvl];
    int cs = (m + nch - 1) / nch;
    start = chunk * cs;
    end = min(m, start + cs);
  } else if (m == 0) {
    float* so = A.seg01[lvl] + (size_t)bs * CF;
#pragma unroll
    for (int k = 0; k < 2; k++)
      if (val[k]) *(float4*)(so + (t + k * 256) * 4) = make_float4(0.f, 0.f, 0.f, 0.f);
    return;
  }

  float ax[2][4] = {};
  if (start < end) {
    const int* pl = A.pt[lvl] + (size_t)b * N + A.segoff[lvl][bs];
    int p = start;
    for (; p + 8 <= end; p += 8) {
      int n[8];
#pragma unroll
      for (int q = 0; q < 8; q++) n[q] = pl[p + q];
#pragma unroll
      for (int k = 0; k < 2; k++) if (val[k]) {
        int r[8];
#pragma unroll
        for (int q = 0; q < 8; q++) r[q] = cim[k] ? cim[k][n[q]] : n[q];
        float4 v[8];
#pragma unroll
        for (int q = 0; q < 8; q++) v[q] = *(const float4*)(xs[k] + (size_t)r[q] * str[k]);
#pragma unroll
        for (int q = 0; q < 8; q++) {
          ax[k][0] += v[q].x; ax[k][1] += v[q].y; ax[k][2] += v[q].z; ax[k][3] += v[q].w;
        }
      }
    }
    for (; p + 4 <= end; p += 4) {
      int n0 = pl[p], n1 = pl[p + 1], n2 = pl[p + 2], n3 = pl[p + 3];
#pragma unroll
      for (int k = 0; k < 2; k++) if (val[k]) {
        int r0 = cim[k] ? cim[k][n0] : n0;
        int r1 = cim[k] ? cim[k][n1] : n1;
        int r2 = cim[k] ? cim[k][n2] : n2;
        int r3 = cim[k] ? cim[k][n3] : n3;
        float4 v0 = *(const float4*)(xs[k] + (size_t)r0 * str[k]);
        float4 v1 = *(const float4*)(xs[k] + (size_t)r1 * str[k]);
        float4 v2 = *(const float4*)(xs[k] + (size_t)r2 * str[k]);
        float4 v3 = *(const float4*)(xs[k] + (size_t)r3 * str[k]);
        ax[k][0] += (v0.x + v1.x) + (v2.x + v3.x);
        ax[k][1] += (v0.y + v1.y) + (v2.y + v3.y);
        ax[k][2] += (v0.z + v1.z) + (v2.z + v3.z);
        ax[k][3] += (v0.w + v1.w) + (v2.w + v3.w);
      }
    }
    for (; p < end; p++) {
      int n0 = pl[p];
#pragma unroll
      for (int k = 0; k < 2; k++) if (val[k]) {
        int r0 = cim[k] ? cim[k][n0] : n0;
        float4 v0 = *(const float4*)(xs[k] + (size_t)r0 * str[k]);
        ax[k][0] += v0.x; ax[k][1] += v0.y; ax[k][2] += v0.z; ax[k][3] += v0.w;
      }
    }
  }

  if (direct) {
    float* so = A.seg01[lvl] + (size_t)bs * CF;
#pragma unroll
    for (int k = 0; k < 2; k++) if (val[k]) {
      int c4 = (t + k * 256) * 4;
      *(float4*)(so + c4) = make_float4(ax[k][0], ax[k][1], ax[k][2], ax[k][3]);
    }
  } else {
    unsigned short* po = A.part[lvl] + ((size_t)chunk * 1024 + bs) * CF;
#pragma unroll
    for (int k = 0; k < 2; k++) if (val[k]) {
      int c4 = (t + k * 256) * 4;
      u16x4 o = {f2bf(ax[k][0]), f2bf(ax[k][1]), f2bf(ax[k][2]), f2bf(ax[k][3])};
      *(u16x4*)(po + c4) = o;
    }
  }
}

// ---------------- combine partials + scale + bf16 + chunk-swizzle + K-pad ----------------
struct CsArgs {
  const float* sg[2];              // levels 0,1: fp32 seg sums
  const unsigned short* pp[5];     // levels 2..4: bf16 partials [NC][1024][CF]
  unsigned short* sb[5];
  const float* scl;
  int CF[5]; int KP[5]; int NC[5];
};

__global__ __launch_bounds__(256)
void conv_seg_k(CsArgs a) {
  int row = blockIdx.x;            // 0..5119
  int lvl = row >> 10;
  int rl  = row & 1023;
  int CF = a.CF[lvl], KP = a.KP[lvl];
  int c = threadIdx.x;
  if (c >= (KP >> 3)) return;
  float s = a.scl[row];
  int w = c & 7, blk = c >> 3;
  int k0 = blk * 64 + ((w ^ (rl & 7)) << 3);
  u16x8 o = {0, 0, 0, 0, 0, 0, 0, 0};
  if (k0 < CF) {
    float acc[8] = {};
    if (lvl <= 1) {
      const float* src = a.sg[lvl] + (size_t)rl * CF + k0;
      float4 v0 = *(const float4*)src;
      float4 v1 = *(const float4*)(src + 4);
      acc[0] = v0.x; acc[1] = v0.y; acc[2] = v0.z; acc[3] = v0.w;
      acc[4] = v1.x; acc[5] = v1.y; acc[6] = v1.z; acc[7] = v1.w;
    } else {
      int nc = a.NC[lvl];
      const unsigned short* base = a.pp[lvl] + (size_t)rl * CF + k0;
      for (int n = 0; n < nc; n++) {
        u16x8 v = *(const u16x8*)(base + (size_t)n * 1024 * CF);
#pragma unroll
        for (int e = 0; e < 8; e++) acc[e] += bf2f(v[e]);
      }
    }
#pragma unroll
    for (int e = 0; e < 8; e++) o[e] = f2bf(acc[e] * s);
  }
  *(u16x8*)(a.sb[lvl] + (size_t)rl * KP + c * 8) = o;
}

// ---------------- W -> Wt bf16 transposed+swizzled via LDS tiles (coalesced R+W) ----------------
// tile = 64 k-rows x 64 n-cols; output chunk (n, c=kb*8+w2): k0 = kb*64 + ((w2^(n&7))<<3)
struct CwArgs { const float* w[5]; unsigned short* wt[5]; int CF[5]; int KP[5]; };

__global__ __launch_bounds__(256)
void conv_wtt_k(CwArgs a) {
  int lvl = blockIdx.y;
  int KP = a.KP[lvl], CF = a.CF[lvl];
  int ntiles = 12 * (KP >> 6);
  int tile = blockIdx.x;
  if (tile >= ntiles) return;
  int kb  = tile / 12;           // 64-k block
  int nb0 = tile - kb * 12;      // 64-n block
  int t = threadIdx.x;

  __shared__ float lds[64][65];

  const float* wsrc = a.w[lvl];
#pragma unroll
  for (int e = 0; e < 4; e++) {
    int f = e * 256 + t;         // float4 id in tile, row-major
    int row = f >> 4;            // 0..63
    int c4  = (f & 15) * 4;      // 0..60
    int k = kb * 64 + row;
    float4 v = make_float4(0.f, 0.f, 0.f, 0.f);
    if (k < CF) v = *(const float4*)(wsrc + (size_t)k * HID + nb0 * 64 + c4);
    lds[row][c4 + 0] = v.x; lds[row][c4 + 1] = v.y;
    lds[row][c4 + 2] = v.z; lds[row][c4 + 3] = v.w;
  }
  __syncthreads();

  unsigned short* wt = a.wt[lvl];
#pragma unroll
  for (int h = 0; h < 2; h++) {
    int idx2 = h * 256 + t;      // 0..511 = 64 n x 8 chunks
    int n_loc = idx2 >> 3;
    int w2    = idx2 & 7;
    int kbase = (w2 ^ (n_loc & 7)) << 3;
    u16x8 o;
#pragma unroll
    for (int e = 0; e < 8; e++) o[e] = f2bf(lds[kbase + e][n_loc]);
    int n = nb0 * 64 + n_loc;
    *(u16x8*)(wt + (size_t)n * KP + kb * 64 + w2 * 8) = o;
  }
}

// ---------------- bf16 MFMA GEMM: proj = segbf @ Wt^T + bias ----------------
struct G2Args {
  const unsigned short* sb[5];
  const unsigned short* wt[5];
  const float* bias[5];
  float* proj;
  int KP[5];
  int KIT[5];
};

__global__ __launch_bounds__(256)
void gemm2_k(G2Args g) {
  int lvl = blockIdx.z;
  int n0 = blockIdx.x * 64;
  int m0 = blockIdx.y * 128;
  const char* A = (const char*)g.sb[lvl];
  const char* Bw = (const char*)g.wt[lvl];
  int KP = g.KP[lvl];
  int KIT = g.KIT[lvl];

  __shared__ char smem[49152];     // 2 x (16KB A + 8KB B)

  int t = threadIdx.x;
  int lane = t & 63;
  int w = t >> 6;
  int wm = w >> 1, wn = w & 1;

  f32x4 acc[4][2] = {};

  int rowb = t >> 3;
  int colb = (t & 7) * 16;

  auto stg = [&](int buf, int it) {
    char* base = smem + buf * 24576;
#pragma unroll
    for (int j = 0; j < 4; j++) {
      int row = j * 32 + rowb;
      gl_lds16(A + (size_t)(m0 + row) * (KP * 2) + it * 128 + colb,
               base + j * 4096 + t * 16);
    }
#pragma unroll
    for (int j = 0; j < 2; j++) {
      int row = j * 32 + rowb;
      gl_lds16(Bw + (size_t)(n0 + row) * (KP * 2) + it * 128 + colb,
               base + 16384 + j * 4096 + t * 16);
    }
  };

  int r15 = lane & 15, hi = lane >> 4, sx = (lane & 7) << 4;

  stg(0, 0);
  int cur = 0;
  for (int it = 0; it < KIT; ++it) {
    __syncthreads();
    if (it + 1 < KIT) stg(cur ^ 1, it + 1);
    const char* base = smem + cur * 24576;
    s16x8 af[2][4]; s16x8 bf2v[2][2];
#pragma unroll
    for (int s = 0; s < 2; s++) {
      int cb = (s * 64 + hi * 16) ^ sx;
#pragma unroll
      for (int fm = 0; fm < 4; fm++) {
        int row = wm * 64 + fm * 16 + r15;
        af[s][fm] = *(const s16x8*)(base + row * 128 + cb);
      }
#pragma unroll
      for (int fn = 0; fn < 2; fn++) {
        int row = wn * 32 + fn * 16 + r15;
        bf2v[s][fn] = *(const s16x8*)(base + 16384 + row * 128 + cb);
      }
    }
#pragma unroll
    for (int s = 0; s < 2; s++)
#pragma unroll
      for (int fm = 0; fm < 4; fm++)
#pragma unroll
        for (int fn = 0; fn < 2; fn++)
          acc[fm][fn] = __builtin_amdgcn_mfma_f32_16x16x32_bf16(af[s][fm], bf2v[s][fn], acc[fm][fn], 0, 0, 0);
    cur ^= 1;
  }

  const float* bias = g.bias[lvl];
  float* proj = g.proj + ((size_t)lvl * 1024 + m0) * HID;
#pragma unroll
  for (int fm = 0; fm < 4; fm++)
#pragma unroll
    for (int fn = 0; fn < 2; fn++) {
      int col = n0 + wn * 32 + fn * 16 + r15;
      int rb = wm * 64 + fm * 16 + hi * 4;
      float bi = bias[col];
      f32x4 v = acc[fm][fn];
#pragma unroll
      for (int r = 0; r < 4; r++)
        proj[(size_t)(rb + r) * HID + col] = v[r] + bi;
    }
}

// ---------------- LayerNorm over HID=768 (fp32 in/out) ----------------
struct LnArgs { const float* g[5]; const float* be[5]; };

__global__ __launch_bounds__(256)
void ln_k(LnArgs la, const float* __restrict__ proj, float* __restrict__ out) {
  int row = blockIdx.x;
  int lvl = row >> 10;
  const float* x = proj + (size_t)row * HID;
  int t = threadIdx.x;
  float v0 = x[t], v1 = x[t + 256], v2 = x[t + 512];
  float s = v0 + v1 + v2;
  float q = v0 * v0 + v1 * v1 + v2 * v2;
#pragma unroll
  for (int d = 32; d >= 1; d >>= 1) { s += __shfl_down(s, d); q += __shfl_down(q, d); }
  __shared__ float ps[4], pq[4];
  int w = t >> 6;
  if ((t & 63) == 0) { ps[w] = s; pq[w] = q; }
  __syncthreads();
  float S = ps[0] + ps[1] + ps[2] + ps[3];
  float Q = pq[0] + pq[1] + pq[2] + pq[3];
  float mean = S * (1.0f / HID);
  float var  = Q * (1.0f / HID) - mean * mean;
  float rs   = rsqrtf(var + 1e-5f);
  const float* g  = la.g[lvl];
  const float* be = la.be[lvl];
  float* o = out + (size_t)row * HID;
  o[t]       = (v0 - mean) * rs * g[t]       + be[t];
  o[t + 256] = (v1 - mean) * rs * g[t + 256] + be[t + 256];
  o[t + 512] = (v2 - mean) * rs * g[t + 512] + be[t + 512];
}

// =====================================================================
extern "C" void kernel_launch(void* const* d_in, const int* in_sizes, int n_in,
                              void* d_out, int out_size, void* d_ws, size_t ws_size,
                              hipStream_t stream) {
  static const int N_[5]  = {256, 1024, 4096, 16384, 65536};
  static const int CN_[5] = {512, 384, 192, 96, 48};
  static const int CF_[5] = {512, 896, 1088, 1184, 1232};
  static const int KP_[5] = {512, 896, 1088, 1216, 1280};   // CF rounded to 64
  static const int NC_[5] = {1, 1, 2, 2, 4};                // point-chunks (no atomics)

  const float* x[5]; const int* p2s[5]; const float* W[5];
  const float* bias[5]; const float* g[5]; const float* be[5];
  for (int i = 0; i < 5; i++) {
    x[i]    = (const float*)d_in[6 * i + 0];
    p2s[i]  = (const int*)  d_in[6 * i + 1];
    W[i]    = (const float*)d_in[6 * i + 2];
    bias[i] = (const float*)d_in[6 * i + 3];
    g[i]    = (const float*)d_in[6 * i + 4];
    be[i]   = (const float*)d_in[6 * i + 5];
  }
  const int* inv[5] = {nullptr, (const int*)d_in[30], (const int*)d_in[31],
                       (const int*)d_in[32], (const int*)d_in[33]};

  int*   wsi = (int*)d_ws;
  float* wsf = (float*)d_ws;
  unsigned short* wsu = (unsigned short*)d_ws;

  // ---- workspace layout (r10-proven chain, unchanged) ----
  const int CNT = 0, CUR = 5120, OFS = 10240, SCL = 15360;
  static const int PT[5]   = {20480, 20992, 23040, 31232, 64000};          // end 195072
  const int CI20 = 195072, CI31 = 203264, CI30 = 236032;
  const int CI42 = 268800, CI41 = 399872, CI40 = 530944;                   // end 662016 (contiguous)
  static const int SG01[2] = {662016, 1186304};                            // fp32 seg lvl0/1, end 2103808
  static const int PPu[5]  = {0, 0, 4207616, 6435840, 8860672};            // bf16 partials, end 13906944
  static const int SBu[5]  = {13906944, 14431232, 15348736, 16462848, 17708032}; // end 19018752 (38.04 MB)
  static const int WTu[5]  = {1324032, 1717248, 2405376, 3240960, 4174848};// over SG01/PP2-head (conv_wtt->gemm)
  const int PROJ = 2578944;                                                // f32 over PP2-tail/PP3/PP4 (gemm->ln)

  hipMemsetAsync(wsi + CNT, 0, (size_t)10240 * 4, stream);   // cnt + cur only

  PreArgs pa{inv[1], inv[2], inv[3], inv[4],
             wsi + CI20, wsi + CI31, wsi + CI30, wsi + CI42, wsi + CI41, wsi + CI40,
             {}, wsi + CNT};
  for (int i = 0; i < 5; i++) pa.p2s[i] = p2s[i];
  pre_k<<<1354, 256, 0, stream>>>(pa);

  scan_k<<<10, 512, 0, stream>>>(wsi + CNT, wsi + OFS, wsf + SCL);

  ScArgs sc{};
  for (int i = 0; i < 5; i++) { sc.p2s[i] = p2s[i]; sc.pt[i] = wsi + PT[i]; }
  sc.cur = wsi + CUR; sc.off = wsi + OFS;
  scat_all_k<<<682, 256, 0, stream>>>(sc);

  const int* cimap[5][5] = {};
  cimap[1][0] = inv[1];
  cimap[2][1] = inv[2]; cimap[2][0] = wsi + CI20;
  cimap[3][2] = inv[3]; cimap[3][1] = wsi + CI31; cimap[3][0] = wsi + CI30;
  cimap[4][3] = inv[4]; cimap[4][2] = wsi + CI42; cimap[4][1] = wsi + CI41; cimap[4][0] = wsi + CI40;

  int offs[5][5] = {};
  for (int i = 1; i < 5; i++)
    for (int j = i - 1; j >= 0; j--) offs[i][j] = CN_[i] + offs[i - 1][j];

  RedAll ra{};
  for (int i = 0; i < 5; i++) {
    int d = 0;
    for (int j = i; j >= 0; j--) {
      ra.x[i][d]      = x[j];
      ra.ci[i][d]     = (j == i) ? nullptr : cimap[i][j];
      ra.Njl[i][d]    = N_[j];
      ra.CN[i][d]     = CN_[j];
      ra.colOFF[i][d] = offs[i][j];
      d++;
    }
    ra.nb[i] = d; ra.N[i] = N_[i]; ra.CF[i] = CF_[i]; ra.nchunk[i] = NC_[i];
    ra.pt[i] = wsi + PT[i]; ra.cnt[i] = wsi + CNT + i * 1024;
    ra.segoff[i] = wsi + OFS + i * 1024;
    ra.part[i] = (i >= 2) ? (wsu + PPu[i]) : nullptr;
  }
  ra.seg01[0] = wsf + SG01[0]; ra.seg01[1] = wsf + SG01[1];
  reduce3_k<<<10240, 256, 0, stream>>>(ra);

  CsArgs ca{};
  ca.sg[0] = wsf + SG01[0]; ca.sg[1] = wsf + SG01[1];
  for (int i = 0; i < 5; i++) {
    ca.pp[i] = (i >= 2) ? (wsu + PPu[i]) : nullptr;
    ca.sb[i] = wsu + SBu[i];
    ca.CF[i] = CF_[i]; ca.KP[i] = KP_[i]; ca.NC[i] = NC_[i];
  }
  ca.scl = wsf + SCL;
  conv_seg_k<<<5120, 256, 0, stream>>>(ca);

  // W -> bf16 transposed via LDS tiles (over dead SG01/PP2-head; AFTER conv_seg)
  CwArgs cw{};
  for (int i = 0; i < 5; i++) { cw.w[i] = W[i]; cw.wt[i] = wsu + WTu[i]; cw.CF[i] = CF_[i]; cw.KP[i] = KP_[i]; }
  conv_wtt_k<<<dim3(240, 5), 256, 0, stream>>>(cw);

  G2Args ga{};
  for (int i = 0; i < 5; i++) {
    ga.sb[i] = wsu + SBu[i]; ga.wt[i] = wsu + WTu[i]; ga.bias[i] = bias[i];
    ga.KP[i] = KP_[i]; ga.KIT[i] = KP_[i] >> 6;
  }
  ga.proj = wsf + PROJ;
  gemm2_k<<<dim3(12, 8, 5), 256, 0, stream>>>(ga);

  LnArgs la{};
  for (int i = 0; i < 5; i++) { la.g[i] = g[i]; la.be[i] = be[i]; }
  ln_k<<<5120, 256, 0, stream>>>(la, wsf + PROJ, (float*)d_out);
}